// Round 16
// baseline (148.511 us; speedup 1.0000x reference)
//
#include <hip/hip_runtime.h>

// Problem: BS=64, N=1024, XC=1024, K=256, YS=768
//   y_k[b,k]   = sum_s y[b,s] * W_y[k,s]
//   z[b,n,k]   = tanh( sum_c x[b,n,c]*W_ch[k,c] + b_ch[k] + y_k[b,k] )
//   out[b*n,k] = softmax_k(z)
// R16: ZERO-BARRIER, ZERO-LDS kernel. Wave owns 32 rows x 256 cols:
//   A private (global->reg f32, pack to bf16; R14's proven mapping),
//   B private (global->reg from bf16 fragment-ordered ws; R9's mapping,
//   each fragment reused by the wave's 2 row-groups), softmax wave-private.
//   No s_barrier / __syncthreads anywhere -> 32 unrolled K32-steps are one
//   SSA DAG the compiler can pipeline freely with counted vmcnt.
//   Grid 512 (2 blocks/CU, single generation). t0 K-phase rotation kept.

#define XC    1024
#define KOUT  256

typedef float        f32x4_t  __attribute__((ext_vector_type(4)));
typedef unsigned int u32x4_t  __attribute__((ext_vector_type(4)));
typedef unsigned int u32x2_t  __attribute__((ext_vector_type(2)));
typedef __bf16       bf16x8_t __attribute__((ext_vector_type(8)));

__device__ __forceinline__ unsigned short f2bf(float f) {
  unsigned int u = __float_as_uint(f);
  u += 0x7fffu + ((u >> 16) & 1u);        // RNE (prep kernel)
  return (unsigned short)(u >> 16);
}

// biased round-half-away pack (accuracy-verified R12-R15: absmax 6.1e-5)
__device__ __forceinline__ unsigned int pack2bf(float a, float b) {
  unsigned int ua = __float_as_uint(a) + 0x8000u;
  unsigned int ub = __float_as_uint(b) + 0x8000u;
  return (ua >> 16) | (ub & 0xffff0000u);
}

__device__ __forceinline__ float fast_tanh(float v) {
  float e = __expf(2.0f * v);
  return 1.0f - 2.0f / (e + 1.0f);
}

// ---- prep kernel: unchanged (wbf frag-order cvt + bias GEMV)
__global__ void prep_kernel(const float* __restrict__ Wch,
                            const float* __restrict__ y,
                            const float* __restrict__ Wy,
                            const float* __restrict__ bch,
                            unsigned short* __restrict__ wbf,
                            float* __restrict__ biasws) {
  if (blockIdx.x < 256) {
    const int k = blockIdx.x;
    const int u = threadIdx.x;
    f32x4_t v = ((const f32x4_t*)(Wch + k * XC))[u];
    const int c0   = u << 2;
    const int t    = c0 >> 6;
    const int ch   = (c0 & 63) >> 3;
    const int kk   = ch >> 2;
    const int lg   = ch & 3;
    const int half = (c0 >> 2) & 1;
    const int wv   = k >> 6;
    const int ni   = (k >> 4) & 3;
    const int lr   = k & 15;
    const int lane = (lg << 4) | lr;
    unsigned int lo = (unsigned int)f2bf(v.x) | ((unsigned int)f2bf(v.y) << 16);
    unsigned int hi = (unsigned int)f2bf(v.z) | ((unsigned int)f2bf(v.w) << 16);
    char* p = (char*)wbf +
              ((size_t)((((t << 2) + wv) * 2 + kk) * 4 + ni) << 10) +
              (lane << 4) + (half << 3);
    *(u32x2_t*)p = (u32x2_t){lo, hi};
  } else {
    __shared__ __align__(16) float ys[768];
    const int b = blockIdx.x - 256;
    const int k = threadIdx.x;
    for (int i = k; i < 768; i += 256) ys[i] = y[b * 768 + i];
    __syncthreads();
    const f32x4_t* w4 = (const f32x4_t*)(Wy + k * 768);
    const f32x4_t* y4 = (const f32x4_t*)ys;
    float s = 0.f;
#pragma unroll 8
    for (int i = 0; i < 192; ++i) {
      f32x4_t w = w4[i], a = y4[i];
      s = fmaf(w.x, a.x, s); s = fmaf(w.y, a.y, s);
      s = fmaf(w.z, a.z, s); s = fmaf(w.w, a.w, s);
    }
    biasws[b * 256 + k] = s + bch[k];
  }
}

// ---- main fused kernel: 4 independent waves x (32 rows x 256 cols).
__global__ __launch_bounds__(256, 2) void fused_kernel(
    const float* __restrict__ x, const unsigned short* __restrict__ wbf,
    const float* __restrict__ bias, float* __restrict__ out) {
  const int tid = threadIdx.x;
  const int l   = tid & 63;
  const int w   = tid >> 6;            // wave 0..3 -> rows [32w, 32w+32)
  const int lr  = l & 15;              // A: row within 16; B: col within 16
  const int lg  = l >> 4;              // k-window (both operands)
  const int m0  = blockIdx.x << 7;     // 128 rows/block
  const int bidx = m0 >> 10;
  const int t0  = blockIdx.x & 15;     // K-phase rotation (R9, +6%)

  f32x4_t acc0[16], acc1[16];          // 2 row-frags x 16 col-frags
#pragma unroll
  for (int i = 0; i < 16; ++i) {
    acc0[i] = (f32x4_t){0.f, 0.f, 0.f, 0.f};
    acc1[i] = (f32x4_t){0.f, 0.f, 0.f, 0.f};
  }

  // A: lane covers rows m0 + w*32 + {0,16} + lr, k-window lg*8
  const char* xrow0 = (const char*)x +
      ((size_t)(m0 + (w << 5) + lr) << 12) + (lg << 5);
  const char* xrow1 = xrow0 + (16u << 12);
  const char* wsrc  = (const char*)wbf + (l << 4);
  f32x4_t avE0[2], avE1[2], avO0[2], avO1[2];   // 2-deep A prefetch, NAMED

  // A load for K32 step s: tile=((s>>1)+t0)&15, half=s&1, window lg*8
#define LOADA2(d0, d1, s_) do {                                              \
    const int off_ = (((((s_) >> 1) + t0) & 15) << 8) + (((s_) & 1) << 7);   \
    d0[0] = *(const f32x4_t*)(xrow0 + off_);                                 \
    d0[1] = *(const f32x4_t*)(xrow0 + off_ + 16);                            \
    d1[0] = *(const f32x4_t*)(xrow1 + off_);                                 \
    d1[1] = *(const f32x4_t*)(xrow1 + off_ + 16);                            \
  } while (0)

#define PACK2(afr, avP)                                                      \
    bf16x8_t afr; {                                                          \
      u32x4_t u_;                                                            \
      u_[0] = pack2bf(avP[0].x, avP[0].y);                                   \
      u_[1] = pack2bf(avP[0].z, avP[0].w);                                   \
      u_[2] = pack2bf(avP[1].x, avP[1].y);                                   \
      u_[3] = pack2bf(avP[1].z, avP[1].w);                                   \
      afr = __builtin_bit_cast(bf16x8_t, u_); }

  // One K32 step: pack A(s); 16 B loads (1KB coalesced each); prefetch
  // A(s+2); 32 MFMA. Order keeps MFMA's B-wait older than the A prefetch.
#define KSTEP(s_, aP0, aP1) do {                                             \
    PACK2(afr0_, aP0)                                                        \
    PACK2(afr1_, aP1)                                                        \
    const char* bt_ = wsrc +                                                 \
        ((size_t)((((s_) >> 1) + t0) & 15) << 15) + (((s_) & 1) << 12);      \
    u32x4_t bf_[16];                                                         \
    _Pragma("unroll")                                                        \
    for (int g = 0; g < 4; ++g)                                              \
      _Pragma("unroll")                                                      \
      for (int ni = 0; ni < 4; ++ni)                                         \
        bf_[(g << 2) | ni] =                                                 \
            *(const u32x4_t*)(bt_ + (g << 13) + (ni << 10));                 \
    if ((s_) + 2 < 32) LOADA2(aP0, aP1, (s_) + 2);                           \
    _Pragma("unroll")                                                        \
    for (int g = 0; g < 4; ++g)                                              \
      _Pragma("unroll")                                                      \
      for (int ni = 0; ni < 4; ++ni) {                                       \
        const int c_ = (g << 2) | ni;                                        \
        bf16x8_t bfr_ = __builtin_bit_cast(bf16x8_t, bf_[c_]);               \
        acc0[c_] = __builtin_amdgcn_mfma_f32_16x16x32_bf16(                  \
            afr0_, bfr_, acc0[c_], 0, 0, 0);                                 \
        acc1[c_] = __builtin_amdgcn_mfma_f32_16x16x32_bf16(                  \
            afr1_, bfr_, acc1[c_], 0, 0, 0);                                 \
      }                                                                      \
  } while (0)

  // prologue: A(0) and A(1) in flight; no barrier anywhere.
  LOADA2(avE0, avE1, 0);
  LOADA2(avO0, avO1, 1);

  KSTEP( 0, avE0, avE1);  KSTEP( 1, avO0, avO1);
  KSTEP( 2, avE0, avE1);  KSTEP( 3, avO0, avO1);
  KSTEP( 4, avE0, avE1);  KSTEP( 5, avO0, avO1);
  KSTEP( 6, avE0, avE1);  KSTEP( 7, avO0, avO1);
  KSTEP( 8, avE0, avE1);  KSTEP( 9, avO0, avO1);
  KSTEP(10, avE0, avE1);  KSTEP(11, avO0, avO1);
  KSTEP(12, avE0, avE1);  KSTEP(13, avO0, avO1);
  KSTEP(14, avE0, avE1);  KSTEP(15, avO0, avO1);
  KSTEP(16, avE0, avE1);  KSTEP(17, avO0, avO1);
  KSTEP(18, avE0, avE1);  KSTEP(19, avO0, avO1);
  KSTEP(20, avE0, avE1);  KSTEP(21, avO0, avO1);
  KSTEP(22, avE0, avE1);  KSTEP(23, avO0, avO1);
  KSTEP(24, avE0, avE1);  KSTEP(25, avO0, avO1);
  KSTEP(26, avE0, avE1);  KSTEP(27, avO0, avO1);
  KSTEP(28, avE0, avE1);  KSTEP(29, avO0, avO1);
  KSTEP(30, avE0, avE1);  KSTEP(31, avO0, avO1);

#undef LOADA2
#undef PACK2
#undef KSTEP

  // ---- epilogue: wave-private tanh + softmax + store. No LDS, no sync.
  // C/D layout (R14-proven): lane holds rows (lg*4+r) of its 16-row frag,
  // col frag c covers cols c*16 + lr.
  float brow[16];
#pragma unroll
  for (int c = 0; c < 16; ++c)
    brow[c] = bias[(bidx << 8) + (c << 4) + lr];

#define EPI(accX, RFBASE) do {                                               \
    _Pragma("unroll")                                                        \
    for (int c = 0; c < 16; ++c)                                             \
      _Pragma("unroll")                                                      \
      for (int r = 0; r < 4; ++r)                                            \
        accX[c][r] = fast_tanh(accX[c][r] + brow[c]);                        \
    _Pragma("unroll")                                                        \
    for (int r = 0; r < 4; ++r) {                                            \
      float m = accX[0][r];                                                  \
      _Pragma("unroll")                                                      \
      for (int c = 1; c < 16; ++c) m = fmaxf(m, accX[c][r]);                 \
      m = fmaxf(m, __shfl_xor(m, 1));                                        \
      m = fmaxf(m, __shfl_xor(m, 2));                                        \
      m = fmaxf(m, __shfl_xor(m, 4));                                        \
      m = fmaxf(m, __shfl_xor(m, 8));                                        \
      float ssum = 0.f;                                                      \
      _Pragma("unroll")                                                      \
      for (int c = 0; c < 16; ++c) {                                         \
        float e = __expf(accX[c][r] - m);                                    \
        accX[c][r] = e;                                                      \
        ssum += e;                                                           \
      }                                                                      \
      ssum += __shfl_xor(ssum, 1);                                           \
      ssum += __shfl_xor(ssum, 2);                                           \
      ssum += __shfl_xor(ssum, 4);                                           \
      ssum += __shfl_xor(ssum, 8);                                           \
      const float rinv = 1.0f / ssum;                                        \
      float* orow = out +                                                    \
          ((size_t)(m0 + (w << 5) + (RFBASE) + (lg << 2) + r) << 8) + lr;    \
      _Pragma("unroll")                                                      \
      for (int c = 0; c < 16; ++c)                                           \
        orow[c << 4] = accX[c][r] * rinv;                                    \
    }                                                                        \
  } while (0)

  EPI(acc0, 0);
  EPI(acc1, 16);

#undef EPI
}

extern "C" void kernel_launch(void* const* d_in, const int* in_sizes, int n_in,
                              void* d_out, int out_size, void* d_ws, size_t ws_size,
                              hipStream_t stream) {
  (void)in_sizes; (void)n_in; (void)out_size; (void)ws_size;
  const float* x   = (const float*)d_in[0];
  const float* y   = (const float*)d_in[1];
  const float* Wch = (const float*)d_in[2];
  const float* bch = (const float*)d_in[3];
  const float* Wy  = (const float*)d_in[4];
  float* out = (float*)d_out;
  unsigned short* wbf = (unsigned short*)d_ws;                 // 512 KB
  float* biasws = (float*)((char*)d_ws + 512 * 1024);          // 64 KB

  hipLaunchKernelGGL(prep_kernel, dim3(320), dim3(256), 0, stream,
                     Wch, y, Wy, bch, wbf, biasws);
  hipLaunchKernelGGL(fused_kernel, dim3(512), dim3(256), 0, stream,
                     x, wbf, biasws, out);
}

// Round 17
// 121.915 us; speedup vs baseline: 1.2182x; 1.2182x over previous
//
#include <hip/hip_runtime.h>

// Problem: BS=64, N=1024, XC=1024, K=256, YS=768
//   y_k[b,k]   = sum_s y[b,s] * W_y[k,s]
//   z[b,n,k]   = tanh( sum_c x[b,n,c]*W_ch[k,c] + b_ch[k] + y_k[b,k] )
//   out[b*n,k] = softmax_k(z)
// bf16 MFMA GEMM (f32 acc) fused with tanh+softmax epilogue.
// R17: R15 structure slimmed (A prefetch depth 2, single B reg-buffer,
//      LOADB after COMPUTE) to fit ~160 VGPR -> __launch_bounds__(256,3):
//      3 INDEPENDENT blocks/CU. Unlike R5 (more waves in ONE barrier
//      domain), independent blocks barrier independently -> when one
//      block drains, the other two keep HBM busy. Tripwire: WRITE_SIZE
//      ballooning = spill.

#define XC    1024
#define KOUT  256
#define NT    16        // K-steps: 1024 / 64
#define LDSZ  16384     // A double-buffer: 2 x 8KB (epilogue scratch aliases)

typedef float        f32x4_t  __attribute__((ext_vector_type(4)));
typedef unsigned int u32x4_t  __attribute__((ext_vector_type(4)));
typedef unsigned int u32x2_t  __attribute__((ext_vector_type(2)));
typedef __bf16       bf16x8_t __attribute__((ext_vector_type(8)));

__device__ __forceinline__ unsigned short f2bf(float f) {
  unsigned int u = __float_as_uint(f);
  u += 0x7fffu + ((u >> 16) & 1u);        // RNE (prep kernel only)
  return (unsigned short)(u >> 16);
}

// biased round-half-away pack (accuracy-verified R12-R16: absmax 6.1e-5)
__device__ __forceinline__ unsigned int pack2bf(float a, float b) {
  unsigned int ua = __float_as_uint(a) + 0x8000u;
  unsigned int ub = __float_as_uint(b) + 0x8000u;
  return (ua >> 16) | (ub & 0xffff0000u);
}

__device__ __forceinline__ float fast_tanh(float v) {
  float e = __expf(2.0f * v);
  return 1.0f - 2.0f / (e + 1.0f);
}

// lgkm-only barrier: ds_writes visible, global loads STAY IN FLIGHT.
#define LGKM_BARRIER() do {                                  \
    asm volatile("s_waitcnt lgkmcnt(0)" ::: "memory");       \
    __builtin_amdgcn_s_barrier();                            \
    __builtin_amdgcn_sched_barrier(0);                       \
  } while (0)

// ---- prep kernel: blocks 0..255 convert W_ch -> fragment-ordered bf16;
//      blocks 256..319 compute bias[b][k] = y[b]·W_y[k] + b_ch[k] (f32).
__global__ void prep_kernel(const float* __restrict__ Wch,
                            const float* __restrict__ y,
                            const float* __restrict__ Wy,
                            const float* __restrict__ bch,
                            unsigned short* __restrict__ wbf,
                            float* __restrict__ biasws) {
  if (blockIdx.x < 256) {
    const int k = blockIdx.x;            // 0..255
    const int u = threadIdx.x;           // 0..255 ; c0 = 4u
    f32x4_t v = ((const f32x4_t*)(Wch + k * XC))[u];
    const int c0   = u << 2;
    const int t    = c0 >> 6;            // K-step tile
    const int ch   = (c0 & 63) >> 3;     // 16B chunk within tile
    const int kk   = ch >> 2;
    const int lg   = ch & 3;
    const int half = (c0 >> 2) & 1;      // which 8B of the 16B chunk
    const int wv   = k >> 6;
    const int ni   = (k >> 4) & 3;
    const int lr   = k & 15;
    const int lane = (lg << 4) | lr;
    unsigned int lo = (unsigned int)f2bf(v.x) | ((unsigned int)f2bf(v.y) << 16);
    unsigned int hi = (unsigned int)f2bf(v.z) | ((unsigned int)f2bf(v.w) << 16);
    char* p = (char*)wbf +
              ((size_t)((((t << 2) + wv) * 2 + kk) * 4 + ni) << 10) +
              (lane << 4) + (half << 3);
    *(u32x2_t*)p = (u32x2_t){lo, hi};
  } else {
    __shared__ __align__(16) float ys[768];
    const int b = blockIdx.x - 256;      // 0..63
    const int k = threadIdx.x;           // 0..255
    for (int i = k; i < 768; i += 256) ys[i] = y[b * 768 + i];
    __syncthreads();
    const f32x4_t* w4 = (const f32x4_t*)(Wy + k * 768);
    const f32x4_t* y4 = (const f32x4_t*)ys;
    float s = 0.f;
#pragma unroll 8
    for (int i = 0; i < 192; ++i) {
      f32x4_t w = w4[i], a = y4[i];
      s = fmaf(w.x, a.x, s); s = fmaf(w.y, a.y, s);
      s = fmaf(w.z, a.z, s); s = fmaf(w.w, a.w, s);
    }
    biasws[b * 256 + k] = s + bch[k];
  }
}

// ---- main fused kernel: 64 rows/block x full 256 cols; BK=64.
__global__ __launch_bounds__(256, 3) void fused_kernel(
    const float* __restrict__ x, const unsigned short* __restrict__ wbf,
    const float* __restrict__ bias, float* __restrict__ out) {
  __shared__ __align__(16) unsigned char smem[LDSZ];
  const int tid = threadIdx.x;
  const int l   = tid & 63;
  const int wv  = tid >> 6;            // wave 0..3 -> output cols [64w,64w+64)
  const int lr  = l & 15;
  const int lg  = l >> 4;
  const int m0  = blockIdx.x << 6;     // first of 64 rows
  const int bidx = m0 >> 10;           // batch index
  const int rr  = tid >> 4;            // A-stage: row-within-16-group
  const int c4  = tid & 15;            // A-stage: float4 column chunk
  const int t0  = blockIdx.x & 15;     // per-block K-phase rotation

  f32x4_t acc[4][4];
#pragma unroll
  for (int i = 0; i < 4; ++i)
#pragma unroll
    for (int j = 0; j < 4; ++j) acc[i][j] = (f32x4_t){0.f, 0.f, 0.f, 0.f};

  const float* xb = x + (size_t)m0 * XC + (size_t)rr * XC + (c4 << 2);
  const char* wsrc = (const char*)wbf + (wv << 13) + (l << 4);
  f32x4_t av0[4], av1[4];              // 2-deep A prefetch, NAMED slots
  bf16x8_t bfr[8];                     // single B reg-buffer [kk*4+nj]

#define LOADA(dst, tt) do {                                                  \
    _Pragma("unroll")                                                        \
    for (int j = 0; j < 4; ++j)                                              \
      dst[j] = *(const f32x4_t*)(xb + (size_t)(j << 4) * XC + ((tt) << 6));  \
  } while (0)

#define LOADB(tt) do {                                                       \
    const char* g = wsrc + (size_t)(tt) * 32768;                             \
    _Pragma("unroll")                                                        \
    for (int f = 0; f < 8; ++f)                                              \
      bfr[f] = __builtin_bit_cast(bf16x8_t, *(const u32x4_t*)(g + (f << 10)));\
  } while (0)

#define WRITEA(src, buf) do {                                                \
    _Pragma("unroll")                                                        \
    for (int j = 0; j < 4; ++j) {                                            \
      const int row = (j << 4) + rr;                                         \
      unsigned int lo = pack2bf(src[j].x, src[j].y);                         \
      unsigned int hi = pack2bf(src[j].z, src[j].w);                         \
      char* p = (char*)smem + ((buf) << 13) + row * 128 +                    \
                (((c4 >> 1) ^ (row & 7)) << 4) + ((c4 & 1) << 3);            \
      *(u32x2_t*)p = (u32x2_t){lo, hi};                                      \
    }                                                                        \
  } while (0)

#define COMPUTE(buf) do {                                                    \
    const u32x4_t* aB = (const u32x4_t*)(smem + ((buf) << 13));              \
    _Pragma("unroll")                                                        \
    for (int kk = 0; kk < 2; ++kk) {                                         \
      const int cs = ((kk << 2) | lg) ^ (lr & 7);                            \
      bf16x8_t afr[4];                                                       \
      _Pragma("unroll")                                                      \
      for (int mi = 0; mi < 4; ++mi)                                         \
        afr[mi] = __builtin_bit_cast(bf16x8_t, aB[(((mi << 4) + lr) << 3) + cs]);\
      _Pragma("unroll")                                                      \
      for (int mi = 0; mi < 4; ++mi)                                         \
        _Pragma("unroll")                                                    \
        for (int nj = 0; nj < 4; ++nj)                                       \
          acc[mi][nj] = __builtin_amdgcn_mfma_f32_16x16x32_bf16(             \
              afr[mi], bfr[(kk << 2) | nj], acc[mi][nj], 0, 0, 0);           \
    }                                                                        \
  } while (0)

  // STEP(s): COMPUTE first (uses bfr loaded last step); then issue B(s+1),
  // A(s+2); then stage A(s+1) (in av[(s+1)&1], loaded last step) + barrier.
  // vmcnt at WRITEA leaves B(s+1)+A(s+2) in flight (12 newer ops).
#define STEP(s, aCur, aNext) do {                                            \
    COMPUTE((s) & 1);                                                        \
    if ((s) + 1 < NT) LOADB((((s) + 1 + t0) & 15));                          \
    if ((s) + 2 < NT) LOADA(aCur, (((s) + 2 + t0) & 15));                    \
    if ((s) + 1 < NT) { WRITEA(aNext, ((s) + 1) & 1); LGKM_BARRIER(); }      \
  } while (0)

  // prologue: B(t0), A(t0), A(t0+1) in flight; stage A(t0) into buf0.
  LOADB(t0);
  LOADA(av0, t0);
  LOADA(av1, (t0 + 1) & 15);
  WRITEA(av0, 0);          // drains B(t0)+A(t0); A(t0+1) stays in flight
  LGKM_BARRIER();

  STEP( 0, av0, av1);
  STEP( 1, av1, av0);
  STEP( 2, av0, av1);
  STEP( 3, av1, av0);
  STEP( 4, av0, av1);
  STEP( 5, av1, av0);
  STEP( 6, av0, av1);
  STEP( 7, av1, av0);
  STEP( 8, av0, av1);
  STEP( 9, av1, av0);
  STEP(10, av0, av1);
  STEP(11, av1, av0);
  STEP(12, av0, av1);
  STEP(13, av1, av0);
  STEP(14, av0, av1);
  STEP(15, av1, av0);

  __syncthreads();             // full drain before scratch aliases A buffer

#undef LOADA
#undef LOADB
#undef WRITEA
#undef COMPUTE
#undef STEP

  // ---- epilogue: tanh, row-softmax over 256 cols, store
  float* wred    = (float*)smem;           // [4 waves][64 rows]
  float* rowstat = (float*)(smem + 1024);  // [64 rows]

  float brow[4];
#pragma unroll
  for (int ni = 0; ni < 4; ++ni)
    brow[ni] = bias[(bidx << 8) + (wv << 6) + (ni << 4) + lr];

#pragma unroll
  for (int mi = 0; mi < 4; ++mi)
#pragma unroll
    for (int ni = 0; ni < 4; ++ni)
#pragma unroll
      for (int r = 0; r < 4; ++r)
        acc[mi][ni][r] = fast_tanh(acc[mi][ni][r] + brow[ni]);

  // per-row max: 4 local cols, then butterfly over the 16-lane col group
#pragma unroll
  for (int mi = 0; mi < 4; ++mi)
#pragma unroll
    for (int r = 0; r < 4; ++r) {
      float m = fmaxf(fmaxf(acc[mi][0][r], acc[mi][1][r]),
                      fmaxf(acc[mi][2][r], acc[mi][3][r]));
      m = fmaxf(m, __shfl_xor(m, 1));
      m = fmaxf(m, __shfl_xor(m, 2));
      m = fmaxf(m, __shfl_xor(m, 4));
      m = fmaxf(m, __shfl_xor(m, 8));
      if (lr == 0) wred[(wv << 6) + (mi << 4) + (lg << 2) + r] = m;
    }
  __syncthreads();
  if (tid < 64)
    rowstat[tid] = fmaxf(fmaxf(wred[tid], wred[64 + tid]),
                         fmaxf(wred[128 + tid], wred[192 + tid]));
  __syncthreads();

  // exp + per-row sum
#pragma unroll
  for (int mi = 0; mi < 4; ++mi)
#pragma unroll
    for (int r = 0; r < 4; ++r) {
      const int row = (mi << 4) + (lg << 2) + r;
      const float m = rowstat[row];
      float s = 0.f;
#pragma unroll
      for (int ni = 0; ni < 4; ++ni) {
        float e = __expf(acc[mi][ni][r] - m);
        acc[mi][ni][r] = e;
        s += e;
      }
      s += __shfl_xor(s, 1);
      s += __shfl_xor(s, 2);
      s += __shfl_xor(s, 4);
      s += __shfl_xor(s, 8);
      if (lr == 0) wred[(wv << 6) + row] = s;
    }
  __syncthreads();
  if (tid < 64)
    rowstat[tid] = 1.0f / (wred[tid] + wred[64 + tid] +
                           wred[128 + tid] + wred[192 + tid]);
  __syncthreads();

  // normalize + store (16 lanes = 64B dense segments)
#pragma unroll
  for (int mi = 0; mi < 4; ++mi)
#pragma unroll
    for (int r = 0; r < 4; ++r) {
      const int row = (mi << 4) + (lg << 2) + r;
      const float rinv = rowstat[row];
      float* orow = out + (size_t)(m0 + row) * KOUT + (wv << 6) + lr;
#pragma unroll
      for (int ni = 0; ni < 4; ++ni)
        orow[ni << 4] = acc[mi][ni][r] * rinv;
    }
}

extern "C" void kernel_launch(void* const* d_in, const int* in_sizes, int n_in,
                              void* d_out, int out_size, void* d_ws, size_t ws_size,
                              hipStream_t stream) {
  (void)in_sizes; (void)n_in; (void)out_size; (void)ws_size;
  const float* x   = (const float*)d_in[0];
  const float* y   = (const float*)d_in[1];
  const float* Wch = (const float*)d_in[2];
  const float* bch = (const float*)d_in[3];
  const float* Wy  = (const float*)d_in[4];
  float* out = (float*)d_out;
  unsigned short* wbf = (unsigned short*)d_ws;                 // 512 KB
  float* biasws = (float*)((char*)d_ws + 512 * 1024);          // 64 KB

  hipLaunchKernelGGL(prep_kernel, dim3(320), dim3(256), 0, stream,
                     Wch, y, Wy, bch, wbf, biasws);
  hipLaunchKernelGGL(fused_kernel, dim3(1024), dim3(256), 0, stream,
                     x, wbf, biasws, out);
}

// Round 18
// 111.288 us; speedup vs baseline: 1.3345x; 1.0955x over previous
//
#include <hip/hip_runtime.h>

// Problem: BS=64, N=1024, XC=1024, K=256, YS=768
//   y_k[b,k]   = sum_s y[b,s] * W_y[k,s]
//   z[b,n,k]   = tanh( sum_c x[b,n,c]*W_ch[k,c] + b_ch[k] + y_k[b,k] )
//   out[b*n,k] = softmax_k(z)
// bf16 MFMA GEMM (f32 acc) fused with tanh+softmax epilogue.
// FINAL (== R15, best measured 110.99us): R9 structure + pack2bf cvt.
//   - 64 rows/block, 4 waves x 64 cols, BK=64, 16 fully-instantiated steps
//   - A: 3-deep named-register prefetch -> XOR-swizzled LDS dbuf
//   - B: fragment-ordered bf16 workspace -> double-buffered registers
//   - lgkm-only barriers (global loads stay in flight across s_barrier)
//   - per-block K-phase rotation t0 = bid & 15 (HBM channel decorrelation)
// Measured A/B history: occupancy/depth/DMA/persistence/zero-barrier all
// regress or null; plateau = strided-A effective BW + staging serial work.

#define XC    1024
#define KOUT  256
#define NT    16        // K-steps: 1024 / 64
#define LDSZ  16384     // A double-buffer: 2 x 8KB (epilogue scratch aliases)

typedef float        f32x4_t  __attribute__((ext_vector_type(4)));
typedef unsigned int u32x4_t  __attribute__((ext_vector_type(4)));
typedef unsigned int u32x2_t  __attribute__((ext_vector_type(2)));
typedef __bf16       bf16x8_t __attribute__((ext_vector_type(8)));

__device__ __forceinline__ unsigned short f2bf(float f) {
  unsigned int u = __float_as_uint(f);
  u += 0x7fffu + ((u >> 16) & 1u);        // RNE (prep kernel only)
  return (unsigned short)(u >> 16);
}

// biased round-half-away pack: 2 floats -> 2 bf16 (0.5-ulp; verified)
__device__ __forceinline__ unsigned int pack2bf(float a, float b) {
  unsigned int ua = __float_as_uint(a) + 0x8000u;
  unsigned int ub = __float_as_uint(b) + 0x8000u;
  return (ua >> 16) | (ub & 0xffff0000u);
}

__device__ __forceinline__ float fast_tanh(float v) {
  float e = __expf(2.0f * v);
  return 1.0f - 2.0f / (e + 1.0f);
}

// lgkm-only barrier: ds_writes visible, global loads STAY IN FLIGHT.
#define LGKM_BARRIER() do {                                  \
    asm volatile("s_waitcnt lgkmcnt(0)" ::: "memory");       \
    __builtin_amdgcn_s_barrier();                            \
    __builtin_amdgcn_sched_barrier(0);                       \
  } while (0)

// ---- prep kernel: blocks 0..255 convert W_ch -> fragment-ordered bf16;
//      blocks 256..319 compute bias[b][k] = y[b]·W_y[k] + b_ch[k] (f32).
__global__ void prep_kernel(const float* __restrict__ Wch,
                            const float* __restrict__ y,
                            const float* __restrict__ Wy,
                            const float* __restrict__ bch,
                            unsigned short* __restrict__ wbf,
                            float* __restrict__ biasws) {
  if (blockIdx.x < 256) {
    const int k = blockIdx.x;            // 0..255
    const int u = threadIdx.x;           // 0..255 ; c0 = 4u
    f32x4_t v = ((const f32x4_t*)(Wch + k * XC))[u];
    const int c0   = u << 2;
    const int t    = c0 >> 6;            // K-step tile
    const int ch   = (c0 & 63) >> 3;     // 16B chunk within tile
    const int kk   = ch >> 2;
    const int lg   = ch & 3;
    const int half = (c0 >> 2) & 1;      // which 8B of the 16B chunk
    const int wv   = k >> 6;
    const int ni   = (k >> 4) & 3;
    const int lr   = k & 15;
    const int lane = (lg << 4) | lr;
    unsigned int lo = (unsigned int)f2bf(v.x) | ((unsigned int)f2bf(v.y) << 16);
    unsigned int hi = (unsigned int)f2bf(v.z) | ((unsigned int)f2bf(v.w) << 16);
    char* p = (char*)wbf +
              ((size_t)((((t << 2) + wv) * 2 + kk) * 4 + ni) << 10) +
              (lane << 4) + (half << 3);
    *(u32x2_t*)p = (u32x2_t){lo, hi};
  } else {
    __shared__ __align__(16) float ys[768];
    const int b = blockIdx.x - 256;      // 0..63
    const int k = threadIdx.x;           // 0..255
    for (int i = k; i < 768; i += 256) ys[i] = y[b * 768 + i];
    __syncthreads();
    const f32x4_t* w4 = (const f32x4_t*)(Wy + k * 768);
    const f32x4_t* y4 = (const f32x4_t*)ys;
    float s = 0.f;
#pragma unroll 8
    for (int i = 0; i < 192; ++i) {
      f32x4_t w = w4[i], a = y4[i];
      s = fmaf(w.x, a.x, s); s = fmaf(w.y, a.y, s);
      s = fmaf(w.z, a.z, s); s = fmaf(w.w, a.w, s);
    }
    biasws[b * 256 + k] = s + bch[k];
  }
}

// ---- main fused kernel: 64 rows/block x full 256 cols; BK=64.
__global__ __launch_bounds__(256, 2) void fused_kernel(
    const float* __restrict__ x, const unsigned short* __restrict__ wbf,
    const float* __restrict__ bias, float* __restrict__ out) {
  __shared__ __align__(16) unsigned char smem[LDSZ];
  const int tid = threadIdx.x;
  const int l   = tid & 63;
  const int wv  = tid >> 6;            // wave 0..3 -> output cols [64w,64w+64)
  const int lr  = l & 15;
  const int lg  = l >> 4;
  const int m0  = blockIdx.x << 6;     // first of 64 rows
  const int bidx = m0 >> 10;           // batch index
  const int rr  = tid >> 4;            // A-stage: row-within-16-group
  const int c4  = tid & 15;            // A-stage: float4 column chunk
  const int t0  = blockIdx.x & 15;     // per-block K-phase rotation

  f32x4_t acc[4][4];
#pragma unroll
  for (int i = 0; i < 4; ++i)
#pragma unroll
    for (int j = 0; j < 4; ++j) acc[i][j] = (f32x4_t){0.f, 0.f, 0.f, 0.f};

  const float* xb = x + (size_t)m0 * XC + (size_t)rr * XC + (c4 << 2);
  const char* wsrc = (const char*)wbf + (wv << 13) + (l << 4);
  f32x4_t av0[4], av1[4], av2[4];      // 3-deep A prefetch, NAMED slots
  bf16x8_t bfrA[8], bfrB[8];           // [kk*4+nj], double-buffered

#define LOADA(dst, tt) do {                                                  \
    _Pragma("unroll")                                                        \
    for (int j = 0; j < 4; ++j)                                              \
      dst[j] = *(const f32x4_t*)(xb + (size_t)(j << 4) * XC + ((tt) << 6));  \
  } while (0)

#define LOADB(dst, tt) do {                                                  \
    const char* g = wsrc + (size_t)(tt) * 32768;                             \
    _Pragma("unroll")                                                        \
    for (int f = 0; f < 8; ++f)                                              \
      dst[f] = __builtin_bit_cast(bf16x8_t, *(const u32x4_t*)(g + (f << 10)));\
  } while (0)

#define WRITEA(src, buf) do {                                                \
    _Pragma("unroll")                                                        \
    for (int j = 0; j < 4; ++j) {                                            \
      const int row = (j << 4) + rr;                                         \
      unsigned int lo = pack2bf(src[j].x, src[j].y);                         \
      unsigned int hi = pack2bf(src[j].z, src[j].w);                         \
      char* p = (char*)smem + ((buf) << 13) + row * 128 +                    \
                (((c4 >> 1) ^ (row & 7)) << 4) + ((c4 & 1) << 3);            \
      *(u32x2_t*)p = (u32x2_t){lo, hi};                                      \
    }                                                                        \
  } while (0)

#define COMPUTE(buf, bsrc) do {                                              \
    const u32x4_t* aB = (const u32x4_t*)(smem + ((buf) << 13));              \
    _Pragma("unroll")                                                        \
    for (int kk = 0; kk < 2; ++kk) {                                         \
      const int cs = ((kk << 2) | lg) ^ (lr & 7);                            \
      bf16x8_t afr[4];                                                       \
      _Pragma("unroll")                                                      \
      for (int mi = 0; mi < 4; ++mi)                                         \
        afr[mi] = __builtin_bit_cast(bf16x8_t, aB[(((mi << 4) + lr) << 3) + cs]);\
      _Pragma("unroll")                                                      \
      for (int mi = 0; mi < 4; ++mi)                                         \
        _Pragma("unroll")                                                    \
        for (int nj = 0; nj < 4; ++nj)                                       \
          acc[mi][nj] = __builtin_amdgcn_mfma_f32_16x16x32_bf16(             \
              afr[mi], bsrc[(kk << 2) | nj], acc[mi][nj], 0, 0, 0);          \
    }                                                                        \
  } while (0)

  // STEP(s): literal control flow; K-tile index rotated by t0 at runtime.
#define STEP(s, bC, bN, aW, aL) do {                                         \
    if ((s) + 1 < NT) LOADB(bN, (((s) + 1 + t0) & 15));                      \
    if ((s) + 3 < NT) LOADA(aL, (((s) + 3 + t0) & 15));                      \
    COMPUTE((s) & 1, bC);                                                    \
    if ((s) + 1 < NT) { WRITEA(aW, ((s) + 1) & 1); LGKM_BARRIER(); }         \
  } while (0)

  // prologue: B(t0), A(t0..t0+2) in flight; stage A(t0) into buf0.
  LOADB(bfrA, t0);
  LOADA(av0, t0);
  LOADA(av1, (t0 + 1) & 15);
  LOADA(av2, (t0 + 2) & 15);
  WRITEA(av0, 0);          // drains B+A(t0); later prefetches stay in flight
  LGKM_BARRIER();

  STEP( 0, bfrA, bfrB, av1, av0);
  STEP( 1, bfrB, bfrA, av2, av1);
  STEP( 2, bfrA, bfrB, av0, av2);
  STEP( 3, bfrB, bfrA, av1, av0);
  STEP( 4, bfrA, bfrB, av2, av1);
  STEP( 5, bfrB, bfrA, av0, av2);
  STEP( 6, bfrA, bfrB, av1, av0);
  STEP( 7, bfrB, bfrA, av2, av1);
  STEP( 8, bfrA, bfrB, av0, av2);
  STEP( 9, bfrB, bfrA, av1, av0);
  STEP(10, bfrA, bfrB, av2, av1);
  STEP(11, bfrB, bfrA, av0, av2);
  STEP(12, bfrA, bfrB, av1, av0);
  STEP(13, bfrB, bfrA, av2, av1);
  STEP(14, bfrA, bfrB, av0, av2);
  STEP(15, bfrB, bfrA, av1, av0);

  __syncthreads();             // full drain before scratch aliases A buffer

#undef LOADA
#undef LOADB
#undef WRITEA
#undef COMPUTE
#undef STEP

  // ---- epilogue: tanh, row-softmax over 256 cols, store
  float* wred    = (float*)smem;           // [4 waves][64 rows]
  float* rowstat = (float*)(smem + 1024);  // [64 rows]

  float brow[4];
#pragma unroll
  for (int ni = 0; ni < 4; ++ni)
    brow[ni] = bias[(bidx << 8) + (wv << 6) + (ni << 4) + lr];

#pragma unroll
  for (int mi = 0; mi < 4; ++mi)
#pragma unroll
    for (int ni = 0; ni < 4; ++ni)
#pragma unroll
      for (int r = 0; r < 4; ++r)
        acc[mi][ni][r] = fast_tanh(acc[mi][ni][r] + brow[ni]);

  // per-row max: 4 local cols, then butterfly over the 16-lane col group
#pragma unroll
  for (int mi = 0; mi < 4; ++mi)
#pragma unroll
    for (int r = 0; r < 4; ++r) {
      float m = fmaxf(fmaxf(acc[mi][0][r], acc[mi][1][r]),
                      fmaxf(acc[mi][2][r], acc[mi][3][r]));
      m = fmaxf(m, __shfl_xor(m, 1));
      m = fmaxf(m, __shfl_xor(m, 2));
      m = fmaxf(m, __shfl_xor(m, 4));
      m = fmaxf(m, __shfl_xor(m, 8));
      if (lr == 0) wred[(wv << 6) + (mi << 4) + (lg << 2) + r] = m;
    }
  __syncthreads();
  if (tid < 64)
    rowstat[tid] = fmaxf(fmaxf(wred[tid], wred[64 + tid]),
                         fmaxf(wred[128 + tid], wred[192 + tid]));
  __syncthreads();

  // exp + per-row sum
#pragma unroll
  for (int mi = 0; mi < 4; ++mi)
#pragma unroll
    for (int r = 0; r < 4; ++r) {
      const int row = (mi << 4) + (lg << 2) + r;
      const float m = rowstat[row];
      float s = 0.f;
#pragma unroll
      for (int ni = 0; ni < 4; ++ni) {
        float e = __expf(acc[mi][ni][r] - m);
        acc[mi][ni][r] = e;
        s += e;
      }
      s += __shfl_xor(s, 1);
      s += __shfl_xor(s, 2);
      s += __shfl_xor(s, 4);
      s += __shfl_xor(s, 8);
      if (lr == 0) wred[(wv << 6) + row] = s;
    }
  __syncthreads();
  if (tid < 64)
    rowstat[tid] = 1.0f / (wred[tid] + wred[64 + tid] +
                           wred[128 + tid] + wred[192 + tid]);
  __syncthreads();

  // normalize + store (16 lanes = 64B dense segments)
#pragma unroll
  for (int mi = 0; mi < 4; ++mi)
#pragma unroll
    for (int r = 0; r < 4; ++r) {
      const int row = (mi << 4) + (lg << 2) + r;
      const float rinv = rowstat[row];
      float* orow = out + (size_t)(m0 + row) * KOUT + (wv << 6) + lr;
#pragma unroll
      for (int ni = 0; ni < 4; ++ni)
        orow[ni << 4] = acc[mi][ni][r] * rinv;
    }
}

extern "C" void kernel_launch(void* const* d_in, const int* in_sizes, int n_in,
                              void* d_out, int out_size, void* d_ws, size_t ws_size,
                              hipStream_t stream) {
  (void)in_sizes; (void)n_in; (void)out_size; (void)ws_size;
  const float* x   = (const float*)d_in[0];
  const float* y   = (const float*)d_in[1];
  const float* Wch = (const float*)d_in[2];
  const float* bch = (const float*)d_in[3];
  const float* Wy  = (const float*)d_in[4];
  float* out = (float*)d_out;
  unsigned short* wbf = (unsigned short*)d_ws;                 // 512 KB
  float* biasws = (float*)((char*)d_ws + 512 * 1024);          // 64 KB

  hipLaunchKernelGGL(prep_kernel, dim3(320), dim3(256), 0, stream,
                     Wch, y, Wy, bch, wbf, biasws);
  hipLaunchKernelGGL(fused_kernel, dim3(1024), dim3(256), 0, stream,
                     x, wbf, biasws, out);
}